// Round 1
// baseline (570.634 us; speedup 1.0000x reference)
//
#include <hip/hip_runtime.h>
#include <math.h>

#define NB 1024
static constexpr float BN_INV = 0.99999500003749975f; // 1/sqrt(1+1e-5)

// ---------------- conv1: 3->32, 32x32, +BN+ReLU+maxpool2 -> [B,32,16,16] ----
__global__ __launch_bounds__(256) void k_conv1(
    const float* __restrict__ x, const float* __restrict__ w,
    const float* __restrict__ bias, const float* __restrict__ g,
    const float* __restrict__ be, float* __restrict__ out) {
  __shared__ float tile[3 * 34 * 34];
  const int b = blockIdx.x;
  const int tid = threadIdx.x;
  const float* xb = x + b * 3 * 32 * 32;
  for (int i = tid; i < 3 * 34 * 34; i += 256) {
    int c = i / 1156;
    int rem = i - c * 1156;
    int r = rem / 34;
    int col = rem - r * 34;
    int iy = r - 1, ix = col - 1;
    float v = 0.f;
    if (iy >= 0 && iy < 32 && ix >= 0 && ix < 32)
      v = xb[(c * 32 + iy) * 32 + ix];
    tile[i] = v;
  }
  __syncthreads();
  const int tx = tid & 15, ty = tid >> 4;
  float win[3][4][4];
#pragma unroll
  for (int c = 0; c < 3; ++c)
#pragma unroll
    for (int r = 0; r < 4; ++r)
#pragma unroll
      for (int cc = 0; cc < 4; ++cc)
        win[c][r][cc] = tile[c * 1156 + (2 * ty + r) * 34 + 2 * tx + cc];

  for (int co = 0; co < 32; ++co) {
    const float* wp = w + co * 27;
    float a00 = 0.f, a01 = 0.f, a10 = 0.f, a11 = 0.f;
#pragma unroll
    for (int c = 0; c < 3; ++c)
#pragma unroll
      for (int ky = 0; ky < 3; ++ky)
#pragma unroll
        for (int kx = 0; kx < 3; ++kx) {
          float wv = wp[c * 9 + ky * 3 + kx];
          a00 = fmaf(win[c][ky][kx], wv, a00);
          a01 = fmaf(win[c][ky][kx + 1], wv, a01);
          a10 = fmaf(win[c][ky + 1][kx], wv, a10);
          a11 = fmaf(win[c][ky + 1][kx + 1], wv, a11);
        }
    float gg = g[co] * BN_INV, bt = be[co], bs = bias[co];
    float v0 = fmaxf(fmaf(gg, a00 + bs, bt), 0.f);
    float v1 = fmaxf(fmaf(gg, a01 + bs, bt), 0.f);
    float v2 = fmaxf(fmaf(gg, a10 + bs, bt), 0.f);
    float v3 = fmaxf(fmaf(gg, a11 + bs, bt), 0.f);
    float m = fmaxf(fmaxf(v0, v1), fmaxf(v2, v3));
    out[((b * 32 + co) * 16 + ty) * 16 + tx] = m;
  }
}

// ---------------- conv2: 32->64, 16x16, +BN+ReLU+maxpool2 -> [B,64,8,8] -----
__global__ __launch_bounds__(256) void k_conv2(
    const float* __restrict__ in, const float* __restrict__ w,
    const float* __restrict__ bias, const float* __restrict__ g,
    const float* __restrict__ be, float* __restrict__ out) {
  __shared__ float tile[32 * 18 * 18];
  const int b = blockIdx.x;
  const int tid = threadIdx.x;
  const float* ib = in + b * 32 * 16 * 16;
  for (int i = tid; i < 32 * 324; i += 256) {
    int c = i / 324;
    int rem = i - c * 324;
    int r = rem / 18;
    int col = rem - r * 18;
    int iy = r - 1, ix = col - 1;
    float v = 0.f;
    if (iy >= 0 && iy < 16 && ix >= 0 && ix < 16)
      v = ib[(c * 16 + iy) * 16 + ix];
    tile[i] = v;
  }
  __syncthreads();
  const int px = tid & 63;
  const int pxx = px & 7, py = px >> 3;
  const int grp = __builtin_amdgcn_readfirstlane(tid >> 6); // 0..3 wave-uniform

#pragma unroll
  for (int chunk = 0; chunk < 2; ++chunk) {
    const int co0 = grp * 16 + chunk * 8;
    float acc[8][4];
#pragma unroll
    for (int i = 0; i < 8; ++i)
#pragma unroll
      for (int p = 0; p < 4; ++p) acc[i][p] = 0.f;

    for (int ci = 0; ci < 32; ++ci) {
      float wn[4][4];
#pragma unroll
      for (int r = 0; r < 4; ++r)
#pragma unroll
        for (int c4 = 0; c4 < 4; ++c4)
          wn[r][c4] = tile[ci * 324 + (2 * py + r) * 18 + 2 * pxx + c4];
#pragma unroll
      for (int i = 0; i < 8; ++i) {
        const float* wp = w + ((co0 + i) * 32 + ci) * 9;
        float wk[9];
#pragma unroll
        for (int k = 0; k < 9; ++k) wk[k] = wp[k];
#pragma unroll
        for (int dy = 0; dy < 2; ++dy)
#pragma unroll
          for (int dx = 0; dx < 2; ++dx) {
            float a = acc[i][dy * 2 + dx];
#pragma unroll
            for (int ky = 0; ky < 3; ++ky)
#pragma unroll
              for (int kx = 0; kx < 3; ++kx)
                a = fmaf(wn[dy + ky][dx + kx], wk[ky * 3 + kx], a);
            acc[i][dy * 2 + dx] = a;
          }
      }
    }
#pragma unroll
    for (int i = 0; i < 8; ++i) {
      int co = co0 + i;
      float gg = g[co] * BN_INV, bt = be[co], bs = bias[co];
      float v0 = fmaxf(fmaf(gg, acc[i][0] + bs, bt), 0.f);
      float v1 = fmaxf(fmaf(gg, acc[i][1] + bs, bt), 0.f);
      float v2 = fmaxf(fmaf(gg, acc[i][2] + bs, bt), 0.f);
      float v3 = fmaxf(fmaf(gg, acc[i][3] + bs, bt), 0.f);
      float m = fmaxf(fmaxf(v0, v1), fmaxf(v2, v3));
      out[((b * 64 + co) * 8 + py) * 8 + pxx] = m;
    }
  }
}

// ---------------- conv3: 64->128, 8x8, +BN+ReLU+avgpool2 -> [B,2048] --------
__global__ __launch_bounds__(256) void k_conv3(
    const float* __restrict__ in, const float* __restrict__ w,
    const float* __restrict__ bias, const float* __restrict__ g,
    const float* __restrict__ be, float* __restrict__ out) {
  __shared__ float tile[64 * 100]; // [ci][10][10]
  const int b = blockIdx.x;
  const int tid = threadIdx.x;
  const float* ib = in + b * 64 * 64;
  for (int i = tid; i < 6400; i += 256) {
    int c = i / 100;
    int rem = i - c * 100;
    int r = rem / 10;
    int col = rem - r * 10;
    int iy = r - 1, ix = col - 1;
    float v = 0.f;
    if (iy >= 0 && iy < 8 && ix >= 0 && ix < 8)
      v = ib[(c * 8 + iy) * 8 + ix];
    tile[i] = v;
  }
  __syncthreads();
  const int px = tid & 15;
  const int pool_x = px & 3, pool_y = px >> 2;
  const int sub = (tid >> 4) & 3;
  const int grp = __builtin_amdgcn_readfirstlane(tid >> 6); // 0..3 uniform
  const int cy = 2 * pool_y + (sub >> 1);
  const int cx = 2 * pool_x + (sub & 1);

#pragma unroll
  for (int iter = 0; iter < 4; ++iter) {
    const int co0 = grp * 32 + iter * 8;
    float acc[8];
#pragma unroll
    for (int i = 0; i < 8; ++i) acc[i] = 0.f;

    for (int ci = 0; ci < 64; ++ci) {
      float wn[9];
#pragma unroll
      for (int ky = 0; ky < 3; ++ky)
#pragma unroll
        for (int kx = 0; kx < 3; ++kx)
          wn[ky * 3 + kx] = tile[ci * 100 + (cy + ky) * 10 + cx + kx];
#pragma unroll
      for (int i = 0; i < 8; ++i) {
        const float* wp = w + ((co0 + i) * 64 + ci) * 9;
        float a = acc[i];
#pragma unroll
        for (int k = 0; k < 9; ++k) a = fmaf(wn[k], wp[k], a);
        acc[i] = a;
      }
    }
#pragma unroll
    for (int i = 0; i < 8; ++i) {
      int co = co0 + i;
      float v = fmaxf(fmaf(g[co] * BN_INV, acc[i] + bias[co], be[co]), 0.f);
      v += __shfl_xor(v, 16);
      v += __shfl_xor(v, 32);
      v *= 0.25f;
      if (sub == 0) out[b * 2048 + co * 16 + pool_y * 4 + pool_x] = v;
    }
  }
}

// ---------------- fr1: [1024,2048] x [512,2048]^T + bias, ReLU --------------
__global__ __launch_bounds__(256) void k_fr1(
    const float* __restrict__ A, const float* __restrict__ W,
    const float* __restrict__ bias, float* __restrict__ C) {
  __shared__ float As[16][68];
  __shared__ float Bs[16][68];
  const int bm = blockIdx.x, bn = blockIdx.y;
  const int tid = threadIdx.x;
  const int tx = tid & 15, ty = tid >> 4;
  const int lr = tid >> 2, lk = tid & 3;
  const float* Ab = A + (bm * 64) * 2048;
  const float* Wb = W + (bn * 64) * 2048;
  float acc[4][4];
#pragma unroll
  for (int i = 0; i < 4; ++i)
#pragma unroll
    for (int j = 0; j < 4; ++j) acc[i][j] = 0.f;

  for (int k0 = 0; k0 < 2048; k0 += 16) {
    float4 av = *(const float4*)(Ab + lr * 2048 + k0 + lk * 4);
    float4 wv = *(const float4*)(Wb + lr * 2048 + k0 + lk * 4);
    As[lk * 4 + 0][lr] = av.x;
    As[lk * 4 + 1][lr] = av.y;
    As[lk * 4 + 2][lr] = av.z;
    As[lk * 4 + 3][lr] = av.w;
    Bs[lk * 4 + 0][lr] = wv.x;
    Bs[lk * 4 + 1][lr] = wv.y;
    Bs[lk * 4 + 2][lr] = wv.z;
    Bs[lk * 4 + 3][lr] = wv.w;
    __syncthreads();
#pragma unroll
    for (int k = 0; k < 16; ++k) {
      float4 a4 = *(const float4*)(&As[k][ty * 4]);
      float4 b4 = *(const float4*)(&Bs[k][tx * 4]);
      float ar[4] = {a4.x, a4.y, a4.z, a4.w};
      float br[4] = {b4.x, b4.y, b4.z, b4.w};
#pragma unroll
      for (int i = 0; i < 4; ++i)
#pragma unroll
        for (int j = 0; j < 4; ++j) acc[i][j] = fmaf(ar[i], br[j], acc[i][j]);
    }
    __syncthreads();
  }
#pragma unroll
  for (int i = 0; i < 4; ++i) {
    int m = bm * 64 + ty * 4 + i;
    int n0 = bn * 64 + tx * 4;
    float4 o;
    o.x = fmaxf(acc[i][0] + bias[n0 + 0], 0.f);
    o.y = fmaxf(acc[i][1] + bias[n0 + 1], 0.f);
    o.z = fmaxf(acc[i][2] + bias[n0 + 2], 0.f);
    o.w = fmaxf(acc[i][3] + bias[n0 + 3], 0.f);
    *(float4*)(C + m * 512 + n0) = o;
  }
}

// ---------------- tail: fr2 + softmax + quantum + head ----------------------
__global__ __launch_bounds__(64) void k_tail(
    const float* __restrict__ H, const float* __restrict__ W2,
    const float* __restrict__ b2, const float* __restrict__ qw,
    const float* __restrict__ h1w, const float* __restrict__ h1b,
    const float* __restrict__ bg, const float* __restrict__ bb,
    const float* __restrict__ h2w, const float* __restrict__ h2b,
    float* __restrict__ out) {
  __shared__ float hbuf[512];
  __shared__ float ybuf[128];
  const int b = blockIdx.x;
  const int lane = threadIdx.x;
  const float* hrow = H + b * 512;
  *(float4*)&hbuf[lane * 4] = *(const float4*)&hrow[lane * 4];
  *(float4*)&hbuf[256 + lane * 4] = *(const float4*)&hrow[256 + lane * 4];
  __syncthreads();

  const int j = lane & 15;     // basis index / logit index
  const int grpk = lane >> 4;  // k-slice 0..3
  float partial = 0.f;
  const float* wrow = W2 + j * 512 + grpk * 128;
  const float* hb = hbuf + grpk * 128;
#pragma unroll
  for (int k = 0; k < 128; k += 4) {
    float4 wv = *(const float4*)&wrow[k];
    partial = fmaf(wv.x, hb[k + 0], partial);
    partial = fmaf(wv.y, hb[k + 1], partial);
    partial = fmaf(wv.z, hb[k + 2], partial);
    partial = fmaf(wv.w, hb[k + 3], partial);
  }
  partial += __shfl_xor(partial, 16);
  partial += __shfl_xor(partial, 32);
  float logit = partial + b2[j];

  // softmax over 16 within each 16-lane group
  float m = logit;
#pragma unroll
  for (int d = 1; d < 16; d <<= 1) m = fmaxf(m, __shfl_xor(m, d));
  float e = expf(logit - m);
  float s = e;
#pragma unroll
  for (int d = 1; d < 16; d <<= 1) s += __shfl_xor(s, d);
  float p = e / s;

  // amplitude encode: abs + L2 normalize (p > 0 already)
  float n2 = p * p;
#pragma unroll
  for (int d = 1; d < 16; d <<= 1) n2 += __shfl_xor(n2, d);
  float amp = p / sqrtf(n2);
  float re = amp, im = 0.f;

#pragma unroll
  for (int l = 0; l < 2; ++l) {
#pragma unroll
    for (int q = 0; q < 4; ++q) {
      float th = qw[l * 4 + q] * 0.5f;
      float c = cosf(th), sn = sinf(th);
      int mask = 1 << (3 - q);
      float pre = __shfl_xor(re, mask);
      float pim = __shfl_xor(im, mask);
      float nre = fmaf(c, re, sn * pim);
      float nim = fmaf(c, im, -sn * pre);
      re = nre;
      im = nim;
    }
    // CNOT ring permutation (pull form: src = inverse image of j)
    int src = j;
    if (src & 1) src ^= 8;  // inverse of CNOT(3,0)
    if (src & 2) src ^= 1;  // inverse of CNOT(2,3)
    if (src & 4) src ^= 2;  // inverse of CNOT(1,2)
    if (src & 8) src ^= 4;  // inverse of CNOT(0,1)
    int srclane = (lane & 48) | src;
    re = __shfl(re, srclane);
    im = __shfl(im, srclane);
  }

  float prob = re * re + im * im;
  float qv[4];
#pragma unroll
  for (int w = 0; w < 4; ++w) {
    float sgn = ((j >> (3 - w)) & 1) ? -1.f : 1.f;
    float cwv = prob * sgn;
    cwv += __shfl_xor(cwv, 1);
    cwv += __shfl_xor(cwv, 2);
    cwv += __shfl_xor(cwv, 4);
    cwv += __shfl_xor(cwv, 8);
    qv[w] = cwv;
  }

  // head FC1: 4 -> 128 (+BN eval + ReLU)
#pragma unroll
  for (int t = 0; t < 2; ++t) {
    int jj = lane + 64 * t;
    float4 hw = *(const float4*)&h1w[jj * 4];
    float y = h1b[jj];
    y = fmaf(hw.x, qv[0], y);
    y = fmaf(hw.y, qv[1], y);
    y = fmaf(hw.z, qv[2], y);
    y = fmaf(hw.w, qv[3], y);
    y = fmaf(bg[jj] * BN_INV, y, bb[jj]);
    ybuf[jj] = fmaxf(y, 0.f);
  }
  __syncthreads();

  // head FC2: 128 -> 100
#pragma unroll
  for (int t = 0; t < 2; ++t) {
    int k = lane + 64 * t;
    if (k < 100) {
      const float* wr = h2w + k * 128;
      float o = h2b[k];
#pragma unroll
      for (int jj = 0; jj < 128; jj += 4) {
        float4 wv = *(const float4*)&wr[jj];
        o = fmaf(wv.x, ybuf[jj + 0], o);
        o = fmaf(wv.y, ybuf[jj + 1], o);
        o = fmaf(wv.z, ybuf[jj + 2], o);
        o = fmaf(wv.w, ybuf[jj + 3], o);
      }
      out[b * 100 + k] = o;
    }
  }
}

extern "C" void kernel_launch(void* const* d_in, const int* in_sizes, int n_in,
                              void* d_out, int out_size, void* d_ws,
                              size_t ws_size, hipStream_t stream) {
  const float* x = (const float*)d_in[0];
  const float* c1w = (const float*)d_in[1];
  const float* c1b = (const float*)d_in[2];
  const float* g1 = (const float*)d_in[3];
  const float* be1 = (const float*)d_in[4];
  const float* c2w = (const float*)d_in[5];
  const float* c2b = (const float*)d_in[6];
  const float* g2 = (const float*)d_in[7];
  const float* be2 = (const float*)d_in[8];
  const float* c3w = (const float*)d_in[9];
  const float* c3b = (const float*)d_in[10];
  const float* g3 = (const float*)d_in[11];
  const float* be3 = (const float*)d_in[12];
  const float* fr1w = (const float*)d_in[13];
  const float* fr1b = (const float*)d_in[14];
  const float* fr2w = (const float*)d_in[15];
  const float* fr2b = (const float*)d_in[16];
  const float* qwts = (const float*)d_in[17];
  const float* h1w = (const float*)d_in[18];
  const float* h1b = (const float*)d_in[19];
  const float* bhg = (const float*)d_in[20];
  const float* bhb = (const float*)d_in[21];
  const float* h2w = (const float*)d_in[22];
  const float* h2b = (const float*)d_in[23];
  float* out = (float*)d_out;

  float* ws = (float*)d_ws;
  // workspace layout (floats); out3 reuses out1's region (dead by then)
  float* out1 = ws;                    // [0, 8388608)   : [1024,32,16,16]
  float* out2 = ws + 8388608;          // [8388608, +4194304) : [1024,64,8,8]
  float* out3 = ws;                    // [0, 2097152)   : [1024,2048]
  float* h1 = ws + 2097152;            // [2097152, +524288)  : [1024,512]

  k_conv1<<<NB, 256, 0, stream>>>(x, c1w, c1b, g1, be1, out1);
  k_conv2<<<NB, 256, 0, stream>>>(out1, c2w, c2b, g2, be2, out2);
  k_conv3<<<NB, 256, 0, stream>>>(out2, c3w, c3b, g3, be3, out3);
  k_fr1<<<dim3(16, 8), 256, 0, stream>>>(out3, fr1w, fr1b, h1);
  k_tail<<<NB, 64, 0, stream>>>(h1, fr2w, fr2b, qwts, h1w, h1b, bhg, bhb, h2w,
                                h2b, out);
}

// Round 2
// 286.023 us; speedup vs baseline: 1.9951x; 1.9951x over previous
//
#include <hip/hip_runtime.h>
#include <math.h>

#define NB 1024
static constexpr float BN_INV = 0.99999500003749975f; // 1/sqrt(1+1e-5)

typedef __attribute__((ext_vector_type(8))) short short8;
typedef __attribute__((ext_vector_type(4))) float f32x4;

__device__ inline short f2bf(float f) {
  union { float f; unsigned u; } v;
  v.f = f;
  unsigned u = v.u;
  u += 0x7fff + ((u >> 16) & 1); // RNE
  return (short)(u >> 16);
}

// ---------------- prepack: weights -> MFMA A-frag order (bf16) + BN fold ----
// wp2: [(off*4+ct)*64+lane]*8+j  <- conv2_w[co=ct*16+(lane&15)][ci=(lane>>4)*8+j][off]
// wp3: [((off*2+half)*8+ct)*64+lane]*8+j <- conv3_w[co=ct*16+(lane&15)][ci=half*32+(lane>>4)*8+j][off]
// scsh: sc2[64], sh2[64], sc3[128], sh3[128]
__global__ void k_prepack(const float* __restrict__ c2w, const float* __restrict__ c2b,
                          const float* __restrict__ g2, const float* __restrict__ be2,
                          const float* __restrict__ c3w, const float* __restrict__ c3b,
                          const float* __restrict__ g3, const float* __restrict__ be3,
                          short* __restrict__ wp2, short* __restrict__ wp3,
                          float* __restrict__ scsh) {
  int i = blockIdx.x * 256 + threadIdx.x;
  int stride = gridDim.x * 256;
  for (int e = i; e < 18432; e += stride) {
    int j = e & 7, lane = (e >> 3) & 63, ct = (e >> 9) & 3, off = e >> 11;
    int co = ct * 16 + (lane & 15), ci = (lane >> 4) * 8 + j;
    wp2[e] = f2bf(c2w[(co * 32 + ci) * 9 + off]);
  }
  for (int e = i; e < 73728; e += stride) {
    int j = e & 7, lane = (e >> 3) & 63, ct = (e >> 9) & 7, oh = e >> 12;
    int half = oh & 1, off = oh >> 1;
    int co = ct * 16 + (lane & 15), ci = half * 32 + (lane >> 4) * 8 + j;
    wp3[e] = f2bf(c3w[(co * 64 + ci) * 9 + off]);
  }
  if (i < 64) {
    float sc = g2[i] * BN_INV;
    scsh[i] = sc;
    scsh[64 + i] = sc * c2b[i] + be2[i];
  } else if (i < 192) {
    int c = i - 64;
    float sc = g3[c] * BN_INV;
    scsh[128 + c] = sc;
    scsh[256 + c] = sc * c3b[c] + be3[c];
  }
}

// ---------------- conv1: 3->32, 32x32, +BN+ReLU+maxpool2 -> [B,32,16,16] ----
__global__ __launch_bounds__(256) void k_conv1(
    const float* __restrict__ x, const float* __restrict__ w,
    const float* __restrict__ bias, const float* __restrict__ g,
    const float* __restrict__ be, float* __restrict__ out) {
  __shared__ float tile[3 * 34 * 34];
  const int b = blockIdx.x;
  const int tid = threadIdx.x;
  const float* xb = x + b * 3 * 32 * 32;
  for (int i = tid; i < 3 * 34 * 34; i += 256) {
    int c = i / 1156;
    int rem = i - c * 1156;
    int r = rem / 34;
    int col = rem - r * 34;
    int iy = r - 1, ix = col - 1;
    float v = 0.f;
    if (iy >= 0 && iy < 32 && ix >= 0 && ix < 32)
      v = xb[(c * 32 + iy) * 32 + ix];
    tile[i] = v;
  }
  __syncthreads();
  const int tx = tid & 15, ty = tid >> 4;
  float win[3][4][4];
#pragma unroll
  for (int c = 0; c < 3; ++c)
#pragma unroll
    for (int r = 0; r < 4; ++r)
#pragma unroll
      for (int cc = 0; cc < 4; ++cc)
        win[c][r][cc] = tile[c * 1156 + (2 * ty + r) * 34 + 2 * tx + cc];

  for (int co = 0; co < 32; ++co) {
    const float* wp = w + co * 27;
    float a00 = 0.f, a01 = 0.f, a10 = 0.f, a11 = 0.f;
#pragma unroll
    for (int c = 0; c < 3; ++c)
#pragma unroll
      for (int ky = 0; ky < 3; ++ky)
#pragma unroll
        for (int kx = 0; kx < 3; ++kx) {
          float wv = wp[c * 9 + ky * 3 + kx];
          a00 = fmaf(win[c][ky][kx], wv, a00);
          a01 = fmaf(win[c][ky][kx + 1], wv, a01);
          a10 = fmaf(win[c][ky + 1][kx], wv, a10);
          a11 = fmaf(win[c][ky + 1][kx + 1], wv, a11);
        }
    float gg = g[co] * BN_INV, bt = be[co], bs = bias[co];
    float v0 = fmaxf(fmaf(gg, a00 + bs, bt), 0.f);
    float v1 = fmaxf(fmaf(gg, a01 + bs, bt), 0.f);
    float v2 = fmaxf(fmaf(gg, a10 + bs, bt), 0.f);
    float v3 = fmaxf(fmaf(gg, a11 + bs, bt), 0.f);
    float m = fmaxf(fmaxf(v0, v1), fmaxf(v2, v3));
    out[((b * 32 + co) * 16 + ty) * 16 + tx] = m;
  }
}

// ---------------- conv2 (MFMA): 32->64, 16x16, +BN+ReLU+maxpool -> bf16 [B,64,8,8]
// LDS inT[y 18][x 18][ci 40pad] bf16. Wave w owns rows 4w..4w+3 (4 px-tiles of
// one 16-wide row each), all 4 co-tiles. K=32 per MFMA (full ci), 9 offsets.
__global__ __launch_bounds__(256) void k_conv2m(
    const float* __restrict__ in /* out1, [B,32,16,16] f32 */,
    const short* __restrict__ wp2, const float* __restrict__ scsh,
    short* __restrict__ out2 /* bf16 [B,64,8,8] */) {
  __shared__ __align__(16) short inT[18 * 18 * 40]; // 25.9 KB
  const int b = blockIdx.x;
  const int tid = threadIdx.x;
  const int w = tid >> 6, lane = tid & 63, q = lane >> 4, n = lane & 15;

  for (int i = tid; i < 18 * 18 * 40 / 2; i += 256) ((int*)inT)[i] = 0;
  __syncthreads();
  const float* ib = in + (size_t)b * 8192;
  for (int i = tid; i < 8192; i += 256) {
    int ci = i >> 8, y = (i >> 4) & 15, x = i & 15;
    inT[((y + 1) * 18 + (x + 1)) * 40 + ci] = f2bf(ib[i]);
  }
  __syncthreads();

  const short8* wv = (const short8*)wp2;
  f32x4 acc[4][4]; // [t][ct]
#pragma unroll
  for (int t = 0; t < 4; ++t)
#pragma unroll
    for (int ct = 0; ct < 4; ++ct) acc[t][ct] = (f32x4)0.f;

#pragma unroll
  for (int off = 0; off < 9; ++off) {
    const int ky = off / 3, kx = off % 3;
    short8 a[4];
#pragma unroll
    for (int ct = 0; ct < 4; ++ct) a[ct] = wv[(off * 4 + ct) * 64 + lane];
#pragma unroll
    for (int t = 0; t < 4; ++t) {
      int y = 4 * w + t;
      short8 bf = *(const short8*)&inT[((y + ky) * 18 + (n + kx)) * 40 + q * 8];
#pragma unroll
      for (int ct = 0; ct < 4; ++ct)
        acc[t][ct] =
            __builtin_amdgcn_mfma_f32_16x16x32_bf16(a[ct], bf, acc[t][ct], 0, 0, 0);
    }
  }

  // epilogue: BN+ReLU, maxpool2, store bf16
  const float* sc2 = scsh;
  const float* sh2 = scsh + 64;
#pragma unroll
  for (int ct = 0; ct < 4; ++ct) {
    float vm[4][4];
#pragma unroll
    for (int t = 0; t < 4; ++t)
#pragma unroll
      for (int r = 0; r < 4; ++r) {
        int co = ct * 16 + q * 4 + r;
        float v = fmaf(sc2[co], acc[t][ct][r], sh2[co]);
        v = fmaxf(v, 0.f);
        vm[t][r] = fmaxf(v, __shfl_xor(v, 1));
      }
#pragma unroll
    for (int pp = 0; pp < 2; ++pp)
#pragma unroll
      for (int r = 0; r < 4; ++r) {
        float m = fmaxf(vm[2 * pp][r], vm[2 * pp + 1][r]);
        if ((n & 1) == 0) {
          int co = ct * 16 + q * 4 + r;
          out2[((size_t)b * 64 + co) * 64 + (2 * w + pp) * 8 + (n >> 1)] = f2bf(m);
        }
      }
  }
}

// ---------------- conv3 (MFMA): 64->128, 8x8, +BN+ReLU+avgpool -> f32 [B,2048]
// LDS inT3[y 10][x 10][ci 72pad] bf16. Wave w: co-tiles (w>>1)*4..+3, px-tiles
// (w&1)*2..+1 (each tile = conv rows 2t..2t+1). 18 K-steps (9 off x 2 ci-half).
__global__ __launch_bounds__(256) void k_conv3m(
    const short* __restrict__ in /* out2 bf16 [B,64,8,8] */,
    const short* __restrict__ wp3, const float* __restrict__ scsh,
    float* __restrict__ out3 /* [B,2048] */) {
  __shared__ __align__(16) short inT3[10 * 10 * 72]; // 14.4 KB
  const int b = blockIdx.x;
  const int tid = threadIdx.x;
  const int w = tid >> 6, lane = tid & 63, q = lane >> 4, n = lane & 15;

  for (int i = tid; i < 10 * 10 * 72 / 2; i += 256) ((int*)inT3)[i] = 0;
  __syncthreads();
  const short* ib = in + (size_t)b * 4096;
  for (int i = tid; i < 4096; i += 256) {
    int ci = i >> 6, y = (i >> 3) & 7, x = i & 7;
    inT3[((y + 1) * 10 + (x + 1)) * 72 + ci] = ib[i];
  }
  __syncthreads();

  const short8* wv = (const short8*)wp3;
  f32x4 acc[4][2]; // [c][tt]
#pragma unroll
  for (int c = 0; c < 4; ++c)
#pragma unroll
    for (int tt = 0; tt < 2; ++tt) acc[c][tt] = (f32x4)0.f;

  const int ct0 = (w >> 1) * 4;
  const int t0 = (w & 1) * 2;
#pragma unroll
  for (int off = 0; off < 9; ++off) {
    const int ky = off / 3, kx = off % 3;
#pragma unroll
    for (int half = 0; half < 2; ++half) {
      short8 a[4];
#pragma unroll
      for (int c = 0; c < 4; ++c)
        a[c] = wv[((off * 2 + half) * 8 + ct0 + c) * 64 + lane];
#pragma unroll
      for (int tt = 0; tt < 2; ++tt) {
        int y = 2 * (t0 + tt) + (n >> 3), x = n & 7;
        short8 bf = *(const short8*)&inT3[((y + ky) * 10 + (x + kx)) * 72 +
                                          half * 32 + q * 8];
#pragma unroll
        for (int c = 0; c < 4; ++c)
          acc[c][tt] =
              __builtin_amdgcn_mfma_f32_16x16x32_bf16(a[c], bf, acc[c][tt], 0, 0, 0);
      }
    }
  }

  // epilogue: BN+ReLU, avgpool2, store f32 [co*16 + py*4 + px]
  const float* sc3 = scsh + 128;
  const float* sh3 = scsh + 256;
#pragma unroll
  for (int c = 0; c < 4; ++c) {
    int ct = ct0 + c;
#pragma unroll
    for (int tt = 0; tt < 2; ++tt) {
      int t = t0 + tt;
#pragma unroll
      for (int r = 0; r < 4; ++r) {
        int co = ct * 16 + q * 4 + r;
        float v = fmaf(sc3[co], acc[c][tt][r], sh3[co]);
        v = fmaxf(v, 0.f);
        float s = v + __shfl_xor(v, 1);
        s += __shfl_xor(s, 8);
        if ((n & 9) == 0)
          out3[(size_t)b * 2048 + co * 16 + t * 4 + (n >> 1)] = s * 0.25f;
      }
    }
  }
}

// ---------------- fr1: [1024,2048] x [512,2048]^T + bias, ReLU --------------
__global__ __launch_bounds__(256) void k_fr1(
    const float* __restrict__ A, const float* __restrict__ W,
    const float* __restrict__ bias, float* __restrict__ C) {
  __shared__ float As[16][68];
  __shared__ float Bs[16][68];
  const int bm = blockIdx.x, bn = blockIdx.y;
  const int tid = threadIdx.x;
  const int tx = tid & 15, ty = tid >> 4;
  const int lr = tid >> 2, lk = tid & 3;
  const float* Ab = A + (bm * 64) * 2048;
  const float* Wb = W + (bn * 64) * 2048;
  float acc[4][4];
#pragma unroll
  for (int i = 0; i < 4; ++i)
#pragma unroll
    for (int j = 0; j < 4; ++j) acc[i][j] = 0.f;

  for (int k0 = 0; k0 < 2048; k0 += 16) {
    float4 av = *(const float4*)(Ab + lr * 2048 + k0 + lk * 4);
    float4 wvv = *(const float4*)(Wb + lr * 2048 + k0 + lk * 4);
    As[lk * 4 + 0][lr] = av.x;
    As[lk * 4 + 1][lr] = av.y;
    As[lk * 4 + 2][lr] = av.z;
    As[lk * 4 + 3][lr] = av.w;
    Bs[lk * 4 + 0][lr] = wvv.x;
    Bs[lk * 4 + 1][lr] = wvv.y;
    Bs[lk * 4 + 2][lr] = wvv.z;
    Bs[lk * 4 + 3][lr] = wvv.w;
    __syncthreads();
#pragma unroll
    for (int k = 0; k < 16; ++k) {
      float4 a4 = *(const float4*)(&As[k][ty * 4]);
      float4 b4 = *(const float4*)(&Bs[k][tx * 4]);
      float ar[4] = {a4.x, a4.y, a4.z, a4.w};
      float br[4] = {b4.x, b4.y, b4.z, b4.w};
#pragma unroll
      for (int i = 0; i < 4; ++i)
#pragma unroll
        for (int j = 0; j < 4; ++j) acc[i][j] = fmaf(ar[i], br[j], acc[i][j]);
    }
    __syncthreads();
  }
#pragma unroll
  for (int i = 0; i < 4; ++i) {
    int m = bm * 64 + ty * 4 + i;
    int n0 = bn * 64 + tx * 4;
    float4 o;
    o.x = fmaxf(acc[i][0] + bias[n0 + 0], 0.f);
    o.y = fmaxf(acc[i][1] + bias[n0 + 1], 0.f);
    o.z = fmaxf(acc[i][2] + bias[n0 + 2], 0.f);
    o.w = fmaxf(acc[i][3] + bias[n0 + 3], 0.f);
    *(float4*)(C + m * 512 + n0) = o;
  }
}

// ---------------- tail: fr2 + softmax + quantum + head ----------------------
__global__ __launch_bounds__(64) void k_tail(
    const float* __restrict__ H, const float* __restrict__ W2,
    const float* __restrict__ b2, const float* __restrict__ qw,
    const float* __restrict__ h1w, const float* __restrict__ h1b,
    const float* __restrict__ bg, const float* __restrict__ bb,
    const float* __restrict__ h2w, const float* __restrict__ h2b,
    float* __restrict__ out) {
  __shared__ float hbuf[512];
  __shared__ float ybuf[128];
  const int b = blockIdx.x;
  const int lane = threadIdx.x;
  const float* hrow = H + b * 512;
  *(float4*)&hbuf[lane * 4] = *(const float4*)&hrow[lane * 4];
  *(float4*)&hbuf[256 + lane * 4] = *(const float4*)&hrow[256 + lane * 4];
  __syncthreads();

  const int j = lane & 15;
  const int grpk = lane >> 4;
  float partial = 0.f;
  const float* wrow = W2 + j * 512 + grpk * 128;
  const float* hb = hbuf + grpk * 128;
#pragma unroll
  for (int k = 0; k < 128; k += 4) {
    float4 wv = *(const float4*)&wrow[k];
    partial = fmaf(wv.x, hb[k + 0], partial);
    partial = fmaf(wv.y, hb[k + 1], partial);
    partial = fmaf(wv.z, hb[k + 2], partial);
    partial = fmaf(wv.w, hb[k + 3], partial);
  }
  partial += __shfl_xor(partial, 16);
  partial += __shfl_xor(partial, 32);
  float logit = partial + b2[j];

  float m = logit;
#pragma unroll
  for (int d = 1; d < 16; d <<= 1) m = fmaxf(m, __shfl_xor(m, d));
  float e = expf(logit - m);
  float s = e;
#pragma unroll
  for (int d = 1; d < 16; d <<= 1) s += __shfl_xor(s, d);
  float p = e / s;

  float n2 = p * p;
#pragma unroll
  for (int d = 1; d < 16; d <<= 1) n2 += __shfl_xor(n2, d);
  float amp = p / sqrtf(n2);
  float re = amp, im = 0.f;

#pragma unroll
  for (int l = 0; l < 2; ++l) {
#pragma unroll
    for (int q = 0; q < 4; ++q) {
      float th = qw[l * 4 + q] * 0.5f;
      float c = cosf(th), sn = sinf(th);
      int mask = 1 << (3 - q);
      float pre = __shfl_xor(re, mask);
      float pim = __shfl_xor(im, mask);
      float nre = fmaf(c, re, sn * pim);
      float nim = fmaf(c, im, -sn * pre);
      re = nre;
      im = nim;
    }
    int src = j;
    if (src & 1) src ^= 8;
    if (src & 2) src ^= 1;
    if (src & 4) src ^= 2;
    if (src & 8) src ^= 4;
    int srclane = (lane & 48) | src;
    re = __shfl(re, srclane);
    im = __shfl(im, srclane);
  }

  float prob = re * re + im * im;
  float qv[4];
#pragma unroll
  for (int w = 0; w < 4; ++w) {
    float sgn = ((j >> (3 - w)) & 1) ? -1.f : 1.f;
    float cwv = prob * sgn;
    cwv += __shfl_xor(cwv, 1);
    cwv += __shfl_xor(cwv, 2);
    cwv += __shfl_xor(cwv, 4);
    cwv += __shfl_xor(cwv, 8);
    qv[w] = cwv;
  }

#pragma unroll
  for (int t = 0; t < 2; ++t) {
    int jj = lane + 64 * t;
    float4 hw = *(const float4*)&h1w[jj * 4];
    float y = h1b[jj];
    y = fmaf(hw.x, qv[0], y);
    y = fmaf(hw.y, qv[1], y);
    y = fmaf(hw.z, qv[2], y);
    y = fmaf(hw.w, qv[3], y);
    y = fmaf(bg[jj] * BN_INV, y, bb[jj]);
    ybuf[jj] = fmaxf(y, 0.f);
  }
  __syncthreads();

#pragma unroll
  for (int t = 0; t < 2; ++t) {
    int k = lane + 64 * t;
    if (k < 100) {
      const float* wr = h2w + k * 128;
      float o = h2b[k];
#pragma unroll
      for (int jj = 0; jj < 128; jj += 4) {
        float4 wv = *(const float4*)&wr[jj];
        o = fmaf(wv.x, ybuf[jj + 0], o);
        o = fmaf(wv.y, ybuf[jj + 1], o);
        o = fmaf(wv.z, ybuf[jj + 2], o);
        o = fmaf(wv.w, ybuf[jj + 3], o);
      }
      out[b * 100 + k] = o;
    }
  }
}

extern "C" void kernel_launch(void* const* d_in, const int* in_sizes, int n_in,
                              void* d_out, int out_size, void* d_ws,
                              size_t ws_size, hipStream_t stream) {
  const float* x = (const float*)d_in[0];
  const float* c1w = (const float*)d_in[1];
  const float* c1b = (const float*)d_in[2];
  const float* g1 = (const float*)d_in[3];
  const float* be1 = (const float*)d_in[4];
  const float* c2w = (const float*)d_in[5];
  const float* c2b = (const float*)d_in[6];
  const float* g2 = (const float*)d_in[7];
  const float* be2 = (const float*)d_in[8];
  const float* c3w = (const float*)d_in[9];
  const float* c3b = (const float*)d_in[10];
  const float* g3 = (const float*)d_in[11];
  const float* be3 = (const float*)d_in[12];
  const float* fr1w = (const float*)d_in[13];
  const float* fr1b = (const float*)d_in[14];
  const float* fr2w = (const float*)d_in[15];
  const float* fr2b = (const float*)d_in[16];
  const float* qwts = (const float*)d_in[17];
  const float* h1w = (const float*)d_in[18];
  const float* h1b = (const float*)d_in[19];
  const float* bhg = (const float*)d_in[20];
  const float* bhb = (const float*)d_in[21];
  const float* h2w = (const float*)d_in[22];
  const float* h2b = (const float*)d_in[23];
  float* out = (float*)d_out;

  float* ws = (float*)d_ws;
  // layout (floats):
  //   out1   [0, 8388608)               f32 [1024,32,16,16]
  //   out2bf [8388608, 10485760)        bf16 [1024,64,8,8] (2M floats worth)
  //   out3   [0, 2097152)               f32 [1024,2048] (out1 dead by then)
  //   h1     [10485760, 11010048)       f32 [1024,512]
  //   packs live inside h1's region (dead before fr1 writes h1):
  //     wp2 @10485760 (9216 fl), wp3 @10494976 (36864 fl), scsh @10531840 (384 fl)
  float* out1 = ws;
  short* out2bf = (short*)(ws + 8388608);
  float* out3 = ws;
  float* h1 = ws + 10485760;
  short* wp2 = (short*)(ws + 10485760);
  short* wp3 = (short*)(ws + 10485760 + 9216);
  float* scsh = ws + 10531840;

  k_prepack<<<96, 256, 0, stream>>>(c2w, c2b, g2, be2, c3w, c3b, g3, be3, wp2,
                                    wp3, scsh);
  k_conv1<<<NB, 256, 0, stream>>>(x, c1w, c1b, g1, be1, out1);
  k_conv2m<<<NB, 256, 0, stream>>>(out1, wp2, scsh, out2bf);
  k_conv3m<<<NB, 256, 0, stream>>>(out2bf, wp3, scsh, out3);
  k_fr1<<<dim3(16, 8), 256, 0, stream>>>(out3, fr1w, fr1b, h1);
  k_tail<<<NB, 64, 0, stream>>>(h1, fr2w, fr2b, qwts, h1w, h1b, bhg, bhb, h2w,
                                h2b, out);
}

// Round 3
// 199.610 us; speedup vs baseline: 2.8587x; 1.4329x over previous
//
#include <hip/hip_runtime.h>
#include <math.h>

#define NB 1024
static constexpr float BN_INV = 0.99999500003749975f; // 1/sqrt(1+1e-5)

typedef __attribute__((ext_vector_type(8))) short short8;
typedef __attribute__((ext_vector_type(4))) float f32x4;

__device__ inline short f2bf(float f) {
  union { float f; unsigned u; } v;
  v.f = f;
  unsigned u = v.u;
  u += 0x7fff + ((u >> 16) & 1); // RNE
  return (short)(u >> 16);
}

// ---------------- prepack: conv2/conv3 weights -> MFMA A-frag bf16, BN fold,
// fr1 weights -> plain bf16 [512][2048] ------------------------------------
__global__ void k_prepack(const float* __restrict__ c2w, const float* __restrict__ c2b,
                          const float* __restrict__ g2, const float* __restrict__ be2,
                          const float* __restrict__ c3w, const float* __restrict__ c3b,
                          const float* __restrict__ g3, const float* __restrict__ be3,
                          const float* __restrict__ fr1w,
                          short* __restrict__ wp2, short* __restrict__ wp3,
                          float* __restrict__ scsh, short* __restrict__ wfr1) {
  int i = blockIdx.x * 256 + threadIdx.x;
  int stride = gridDim.x * 256;
  for (int e = i; e < 18432; e += stride) {
    int j = e & 7, lane = (e >> 3) & 63, ct = (e >> 9) & 3, off = e >> 11;
    int co = ct * 16 + (lane & 15), ci = (lane >> 4) * 8 + j;
    wp2[e] = f2bf(c2w[(co * 32 + ci) * 9 + off]);
  }
  for (int e = i; e < 73728; e += stride) {
    int j = e & 7, lane = (e >> 3) & 63, ct = (e >> 9) & 7, oh = e >> 12;
    int half = oh & 1, off = oh >> 1;
    int co = ct * 16 + (lane & 15), ci = half * 32 + (lane >> 4) * 8 + j;
    wp3[e] = f2bf(c3w[(co * 64 + ci) * 9 + off]);
  }
  // fr1_w: 512*2048 = 1048576 f32 -> bf16, two at a time
  for (int e = i; e < 524288; e += stride) {
    float2 f = ((const float2*)fr1w)[e];
    unsigned lo = (unsigned)(unsigned short)f2bf(f.x);
    unsigned hi = (unsigned)(unsigned short)f2bf(f.y);
    ((unsigned*)wfr1)[e] = (hi << 16) | lo;
  }
  if (i < 64) {
    float sc = g2[i] * BN_INV;
    scsh[i] = sc;
    scsh[64 + i] = sc * c2b[i] + be2[i];
  } else if (i < 192) {
    int c = i - 64;
    float sc = g3[c] * BN_INV;
    scsh[128 + c] = sc;
    scsh[256 + c] = sc * c3b[c] + be3[c];
  }
}

// ---------------- conv1: 3->32, 32x32, +BN+ReLU+maxpool2 -> bf16 [B,32,16,16]
__global__ __launch_bounds__(256) void k_conv1(
    const float* __restrict__ x, const float* __restrict__ w,
    const float* __restrict__ bias, const float* __restrict__ g,
    const float* __restrict__ be, short* __restrict__ out) {
  __shared__ float tile[3 * 34 * 34];
  const int b = blockIdx.x;
  const int tid = threadIdx.x;
  const float* xb = x + b * 3 * 32 * 32;
  for (int i = tid; i < 3 * 34 * 34; i += 256) {
    int c = i / 1156;
    int rem = i - c * 1156;
    int r = rem / 34;
    int col = rem - r * 34;
    int iy = r - 1, ix = col - 1;
    float v = 0.f;
    if (iy >= 0 && iy < 32 && ix >= 0 && ix < 32)
      v = xb[(c * 32 + iy) * 32 + ix];
    tile[i] = v;
  }
  __syncthreads();
  const int tx = tid & 15, ty = tid >> 4;
  float win[3][4][4];
#pragma unroll
  for (int c = 0; c < 3; ++c)
#pragma unroll
    for (int r = 0; r < 4; ++r)
#pragma unroll
      for (int cc = 0; cc < 4; ++cc)
        win[c][r][cc] = tile[c * 1156 + (2 * ty + r) * 34 + 2 * tx + cc];

  for (int co = 0; co < 32; ++co) {
    const float* wp = w + co * 27;
    float a00 = 0.f, a01 = 0.f, a10 = 0.f, a11 = 0.f;
#pragma unroll
    for (int c = 0; c < 3; ++c)
#pragma unroll
      for (int ky = 0; ky < 3; ++ky)
#pragma unroll
        for (int kx = 0; kx < 3; ++kx) {
          float wv = wp[c * 9 + ky * 3 + kx];
          a00 = fmaf(win[c][ky][kx], wv, a00);
          a01 = fmaf(win[c][ky][kx + 1], wv, a01);
          a10 = fmaf(win[c][ky + 1][kx], wv, a10);
          a11 = fmaf(win[c][ky + 1][kx + 1], wv, a11);
        }
    float gg = g[co] * BN_INV, bt = be[co], bs = bias[co];
    float v0 = fmaxf(fmaf(gg, a00 + bs, bt), 0.f);
    float v1 = fmaxf(fmaf(gg, a01 + bs, bt), 0.f);
    float v2 = fmaxf(fmaf(gg, a10 + bs, bt), 0.f);
    float v3 = fmaxf(fmaf(gg, a11 + bs, bt), 0.f);
    float m = fmaxf(fmaxf(v0, v1), fmaxf(v2, v3));
    out[((b * 32 + co) * 16 + ty) * 16 + tx] = f2bf(m);
  }
}

// ---------------- conv2 (MFMA): 32->64, 16x16, +BN+ReLU+maxpool -> bf16 -----
__global__ __launch_bounds__(256) void k_conv2m(
    const short* __restrict__ in /* bf16 [B,32,16,16] */,
    const short* __restrict__ wp2, const float* __restrict__ scsh,
    short* __restrict__ out2 /* bf16 [B,64,8,8] */) {
  __shared__ __align__(16) short inT[18 * 18 * 40]; // 25.9 KB
  const int b = blockIdx.x;
  const int tid = threadIdx.x;
  const int w = tid >> 6, lane = tid & 63, q = lane >> 4, n = lane & 15;

  for (int i = tid; i < 18 * 18 * 40 / 2; i += 256) ((int*)inT)[i] = 0;
  __syncthreads();
  const short* ib = in + (size_t)b * 8192;
  for (int i = tid; i < 8192; i += 256) {
    int ci = i >> 8, y = (i >> 4) & 15, x = i & 15;
    inT[((y + 1) * 18 + (x + 1)) * 40 + ci] = ib[i];
  }
  __syncthreads();

  const short8* wv = (const short8*)wp2;
  f32x4 acc[4][4]; // [t][ct]
#pragma unroll
  for (int t = 0; t < 4; ++t)
#pragma unroll
    for (int ct = 0; ct < 4; ++ct) acc[t][ct] = (f32x4)0.f;

#pragma unroll
  for (int off = 0; off < 9; ++off) {
    const int ky = off / 3, kx = off % 3;
    short8 a[4];
#pragma unroll
    for (int ct = 0; ct < 4; ++ct) a[ct] = wv[(off * 4 + ct) * 64 + lane];
#pragma unroll
    for (int t = 0; t < 4; ++t) {
      int y = 4 * w + t;
      short8 bf = *(const short8*)&inT[((y + ky) * 18 + (n + kx)) * 40 + q * 8];
#pragma unroll
      for (int ct = 0; ct < 4; ++ct)
        acc[t][ct] =
            __builtin_amdgcn_mfma_f32_16x16x32_bf16(a[ct], bf, acc[t][ct], 0, 0, 0);
    }
  }

  const float* sc2 = scsh;
  const float* sh2 = scsh + 64;
#pragma unroll
  for (int ct = 0; ct < 4; ++ct) {
    float vm[4][4];
#pragma unroll
    for (int t = 0; t < 4; ++t)
#pragma unroll
      for (int r = 0; r < 4; ++r) {
        int co = ct * 16 + q * 4 + r;
        float v = fmaf(sc2[co], acc[t][ct][r], sh2[co]);
        v = fmaxf(v, 0.f);
        vm[t][r] = fmaxf(v, __shfl_xor(v, 1));
      }
#pragma unroll
    for (int pp = 0; pp < 2; ++pp)
#pragma unroll
      for (int r = 0; r < 4; ++r) {
        float m = fmaxf(vm[2 * pp][r], vm[2 * pp + 1][r]);
        if ((n & 1) == 0) {
          int co = ct * 16 + q * 4 + r;
          out2[((size_t)b * 64 + co) * 64 + (2 * w + pp) * 8 + (n >> 1)] = f2bf(m);
        }
      }
  }
}

// ---------------- conv3 (MFMA): 64->128, 8x8, +BN+ReLU+avgpool -> bf16 [B,2048]
__global__ __launch_bounds__(256) void k_conv3m(
    const short* __restrict__ in /* bf16 [B,64,8,8] */,
    const short* __restrict__ wp3, const float* __restrict__ scsh,
    short* __restrict__ out3 /* bf16 [B,2048] */) {
  __shared__ __align__(16) short inT3[10 * 10 * 72]; // 14.4 KB
  const int b = blockIdx.x;
  const int tid = threadIdx.x;
  const int w = tid >> 6, lane = tid & 63, q = lane >> 4, n = lane & 15;

  for (int i = tid; i < 10 * 10 * 72 / 2; i += 256) ((int*)inT3)[i] = 0;
  __syncthreads();
  const short* ib = in + (size_t)b * 4096;
  for (int i = tid; i < 4096; i += 256) {
    int ci = i >> 6, y = (i >> 3) & 7, x = i & 7;
    inT3[((y + 1) * 10 + (x + 1)) * 72 + ci] = ib[i];
  }
  __syncthreads();

  const short8* wv = (const short8*)wp3;
  f32x4 acc[4][2]; // [c][tt]
#pragma unroll
  for (int c = 0; c < 4; ++c)
#pragma unroll
    for (int tt = 0; tt < 2; ++tt) acc[c][tt] = (f32x4)0.f;

  const int ct0 = (w >> 1) * 4;
  const int t0 = (w & 1) * 2;
#pragma unroll
  for (int off = 0; off < 9; ++off) {
    const int ky = off / 3, kx = off % 3;
#pragma unroll
    for (int half = 0; half < 2; ++half) {
      short8 a[4];
#pragma unroll
      for (int c = 0; c < 4; ++c)
        a[c] = wv[((off * 2 + half) * 8 + ct0 + c) * 64 + lane];
#pragma unroll
      for (int tt = 0; tt < 2; ++tt) {
        int y = 2 * (t0 + tt) + (n >> 3), x = n & 7;
        short8 bf = *(const short8*)&inT3[((y + ky) * 10 + (x + kx)) * 72 +
                                          half * 32 + q * 8];
#pragma unroll
        for (int c = 0; c < 4; ++c)
          acc[c][tt] =
              __builtin_amdgcn_mfma_f32_16x16x32_bf16(a[c], bf, acc[c][tt], 0, 0, 0);
      }
    }
  }

  const float* sc3 = scsh + 128;
  const float* sh3 = scsh + 256;
#pragma unroll
  for (int c = 0; c < 4; ++c) {
    int ct = ct0 + c;
#pragma unroll
    for (int tt = 0; tt < 2; ++tt) {
      int t = t0 + tt;
#pragma unroll
      for (int r = 0; r < 4; ++r) {
        int co = ct * 16 + q * 4 + r;
        float v = fmaf(sc3[co], acc[c][tt][r], sh3[co]);
        v = fmaxf(v, 0.f);
        float s = v + __shfl_xor(v, 1);
        s += __shfl_xor(s, 8);
        if ((n & 9) == 0)
          out3[(size_t)b * 2048 + co * 16 + t * 4 + (n >> 1)] = f2bf(s * 0.25f);
      }
    }
  }
}

// ---------------- fr1 (MFMA): [1024,2048]bf16 x [512,2048]bf16^T +bias,ReLU ->
// f32 [1024,512]. 32x32 tile/block, grid 32x16=512 blocks, BK=64. -------------
__global__ __launch_bounds__(256) void k_fr1m(
    const short* __restrict__ A, const short* __restrict__ W,
    const float* __restrict__ bias, float* __restrict__ C) {
  __shared__ __align__(16) short As[32 * 72];
  __shared__ __align__(16) short Bs[32 * 72];
  const int m0 = blockIdx.x * 32;
  const int n0 = blockIdx.y * 32;
  const int tid = threadIdx.x;
  const int w = tid >> 6, lane = tid & 63, q = lane >> 4, n = lane & 15;
  const int mt = w >> 1, nt = w & 1;
  const int srow = tid >> 3, sc = tid & 7;

  f32x4 acc = (f32x4)0.f;
  const short* Ab = A + (size_t)(m0 + srow) * 2048 + sc * 8;
  const short* Wb = W + (size_t)(n0 + srow) * 2048 + sc * 8;

  for (int k0 = 0; k0 < 2048; k0 += 64) {
    short8 av = *(const short8*)(Ab + k0);
    short8 bv = *(const short8*)(Wb + k0);
    __syncthreads();
    *(short8*)&As[srow * 72 + sc * 8] = av;
    *(short8*)&Bs[srow * 72 + sc * 8] = bv;
    __syncthreads();
#pragma unroll
    for (int kk = 0; kk < 2; ++kk) {
      short8 bfrag = *(const short8*)&Bs[(nt * 16 + n) * 72 + kk * 32 + q * 8];
      short8 afrag = *(const short8*)&As[(mt * 16 + n) * 72 + kk * 32 + q * 8];
      acc = __builtin_amdgcn_mfma_f32_16x16x32_bf16(afrag, bfrag, acc, 0, 0, 0);
    }
  }
#pragma unroll
  for (int r = 0; r < 4; ++r) {
    int m = m0 + mt * 16 + q * 4 + r;
    int nn = n0 + nt * 16 + n;
    C[(size_t)m * 512 + nn] = fmaxf(acc[r] + bias[nn], 0.f);
  }
}

// ---------------- tail: fr2 + softmax + quantum + head ----------------------
__global__ __launch_bounds__(64) void k_tail(
    const float* __restrict__ H, const float* __restrict__ W2,
    const float* __restrict__ b2, const float* __restrict__ qw,
    const float* __restrict__ h1w, const float* __restrict__ h1b,
    const float* __restrict__ bg, const float* __restrict__ bb,
    const float* __restrict__ h2w, const float* __restrict__ h2b,
    float* __restrict__ out) {
  __shared__ float hbuf[512];
  __shared__ float ybuf[128];
  const int b = blockIdx.x;
  const int lane = threadIdx.x;
  const float* hrow = H + b * 512;
  *(float4*)&hbuf[lane * 4] = *(const float4*)&hrow[lane * 4];
  *(float4*)&hbuf[256 + lane * 4] = *(const float4*)&hrow[256 + lane * 4];
  __syncthreads();

  const int j = lane & 15;
  const int grpk = lane >> 4;
  float partial = 0.f;
  const float* wrow = W2 + j * 512 + grpk * 128;
  const float* hb = hbuf + grpk * 128;
#pragma unroll
  for (int k = 0; k < 128; k += 4) {
    float4 wv = *(const float4*)&wrow[k];
    partial = fmaf(wv.x, hb[k + 0], partial);
    partial = fmaf(wv.y, hb[k + 1], partial);
    partial = fmaf(wv.z, hb[k + 2], partial);
    partial = fmaf(wv.w, hb[k + 3], partial);
  }
  partial += __shfl_xor(partial, 16);
  partial += __shfl_xor(partial, 32);
  float logit = partial + b2[j];

  float m = logit;
#pragma unroll
  for (int d = 1; d < 16; d <<= 1) m = fmaxf(m, __shfl_xor(m, d));
  float e = expf(logit - m);
  float s = e;
#pragma unroll
  for (int d = 1; d < 16; d <<= 1) s += __shfl_xor(s, d);
  float p = e / s;

  float n2 = p * p;
#pragma unroll
  for (int d = 1; d < 16; d <<= 1) n2 += __shfl_xor(n2, d);
  float amp = p / sqrtf(n2);
  float re = amp, im = 0.f;

#pragma unroll
  for (int l = 0; l < 2; ++l) {
#pragma unroll
    for (int q = 0; q < 4; ++q) {
      float th = qw[l * 4 + q] * 0.5f;
      float c = cosf(th), sn = sinf(th);
      int mask = 1 << (3 - q);
      float pre = __shfl_xor(re, mask);
      float pim = __shfl_xor(im, mask);
      float nre = fmaf(c, re, sn * pim);
      float nim = fmaf(c, im, -sn * pre);
      re = nre;
      im = nim;
    }
    int src = j;
    if (src & 1) src ^= 8;
    if (src & 2) src ^= 1;
    if (src & 4) src ^= 2;
    if (src & 8) src ^= 4;
    int srclane = (lane & 48) | src;
    re = __shfl(re, srclane);
    im = __shfl(im, srclane);
  }

  float prob = re * re + im * im;
  float qv[4];
#pragma unroll
  for (int w = 0; w < 4; ++w) {
    float sgn = ((j >> (3 - w)) & 1) ? -1.f : 1.f;
    float cwv = prob * sgn;
    cwv += __shfl_xor(cwv, 1);
    cwv += __shfl_xor(cwv, 2);
    cwv += __shfl_xor(cwv, 4);
    cwv += __shfl_xor(cwv, 8);
    qv[w] = cwv;
  }

#pragma unroll
  for (int t = 0; t < 2; ++t) {
    int jj = lane + 64 * t;
    float4 hw = *(const float4*)&h1w[jj * 4];
    float y = h1b[jj];
    y = fmaf(hw.x, qv[0], y);
    y = fmaf(hw.y, qv[1], y);
    y = fmaf(hw.z, qv[2], y);
    y = fmaf(hw.w, qv[3], y);
    y = fmaf(bg[jj] * BN_INV, y, bb[jj]);
    ybuf[jj] = fmaxf(y, 0.f);
  }
  __syncthreads();

#pragma unroll
  for (int t = 0; t < 2; ++t) {
    int k = lane + 64 * t;
    if (k < 100) {
      const float* wr = h2w + k * 128;
      float o = h2b[k];
#pragma unroll
      for (int jj = 0; jj < 128; jj += 4) {
        float4 wv = *(const float4*)&wr[jj];
        o = fmaf(wv.x, ybuf[jj + 0], o);
        o = fmaf(wv.y, ybuf[jj + 1], o);
        o = fmaf(wv.z, ybuf[jj + 2], o);
        o = fmaf(wv.w, ybuf[jj + 3], o);
      }
      out[b * 100 + k] = o;
    }
  }
}

extern "C" void kernel_launch(void* const* d_in, const int* in_sizes, int n_in,
                              void* d_out, int out_size, void* d_ws,
                              size_t ws_size, hipStream_t stream) {
  const float* x = (const float*)d_in[0];
  const float* c1w = (const float*)d_in[1];
  const float* c1b = (const float*)d_in[2];
  const float* g1 = (const float*)d_in[3];
  const float* be1 = (const float*)d_in[4];
  const float* c2w = (const float*)d_in[5];
  const float* c2b = (const float*)d_in[6];
  const float* g2 = (const float*)d_in[7];
  const float* be2 = (const float*)d_in[8];
  const float* c3w = (const float*)d_in[9];
  const float* c3b = (const float*)d_in[10];
  const float* g3 = (const float*)d_in[11];
  const float* be3 = (const float*)d_in[12];
  const float* fr1w = (const float*)d_in[13];
  const float* fr1b = (const float*)d_in[14];
  const float* fr2w = (const float*)d_in[15];
  const float* fr2b = (const float*)d_in[16];
  const float* qwts = (const float*)d_in[17];
  const float* h1w = (const float*)d_in[18];
  const float* h1b = (const float*)d_in[19];
  const float* bhg = (const float*)d_in[20];
  const float* bhb = (const float*)d_in[21];
  const float* h2w = (const float*)d_in[22];
  const float* h2b = (const float*)d_in[23];
  float* out = (float*)d_out;

  float* ws = (float*)d_ws;
  // layout (float offsets), total ~33.7 MB:
  //   out1bf [0, 4194304)        bf16 [1024,32,16,16]
  //   out2bf [4194304, 6291456)  bf16 [1024,64,8,8]
  //   out3bf [6291456, 7340032)  bf16 [1024,2048]
  //   h1     [7340032, 7864320)  f32  [1024,512]
  //   wfr1   [7864320, 8388608)  bf16 [512,2048]
  //   wp2    [8388608, +9216) | wp3 [8397824, +36864) | scsh [8434688, +384)
  short* out1bf = (short*)ws;
  short* out2bf = (short*)(ws + 4194304);
  short* out3bf = (short*)(ws + 6291456);
  float* h1 = ws + 7340032;
  short* wfr1 = (short*)(ws + 7864320);
  short* wp2 = (short*)(ws + 8388608);
  short* wp3 = (short*)(ws + 8397824);
  float* scsh = ws + 8434688;

  k_prepack<<<96, 256, 0, stream>>>(c2w, c2b, g2, be2, c3w, c3b, g3, be3, fr1w,
                                    wp2, wp3, scsh, wfr1);
  k_conv1<<<NB, 256, 0, stream>>>(x, c1w, c1b, g1, be1, out1bf);
  k_conv2m<<<NB, 256, 0, stream>>>(out1bf, wp2, scsh, out2bf);
  k_conv3m<<<NB, 256, 0, stream>>>(out2bf, wp3, scsh, out3bf);
  k_fr1m<<<dim3(32, 16), 256, 0, stream>>>(out3bf, wfr1, fr1b, h1);
  k_tail<<<NB, 64, 0, stream>>>(h1, fr2w, fr2b, qwts, h1w, h1b, bhg, bhb, h2w,
                                h2b, out);
}